// Round 4
// baseline (378.394 us; speedup 1.0000x reference)
//
#include <hip/hip_runtime.h>
#include <hip/hip_bf16.h>

// PartiallyExchangeableNetwork on MI355X (gfx950)
// N=256, M=3, T=4096, ORDER=2 -> L=4094 windows, H=128, OUT=10
//
// h1 = relu(xin @ W1 + b1); h2 = relu(h1 @ W2 + b2); colsum over L.
// Layer 3 folded through the sum: sum_l(h2@W3+b3) = (sum_l h2)@W3 + L*b3 (tail kernel).

#define NN 256
#define MM 3
#define TT 4096
#define LL 4094
#define HH 128
#define CHUNKS 8
#define RPC 512          // rows (windows) per chunk (2 halves of 256)
#define RPH 256          // rows per staged half
#define HALVES 2
#define STEPS 4          // 64-row steps per half
#define SR 64            // rows per step (block tile)

typedef __attribute__((ext_vector_type(8))) short bf16x8;
typedef __attribute__((ext_vector_type(4))) float f32x4;
typedef __attribute__((ext_vector_type(4))) unsigned short u16x4;
typedef __attribute__((ext_vector_type(2))) unsigned int u32x2;

__device__ __forceinline__ unsigned short f2bf(float x) {
    __hip_bfloat16 h = __float2bfloat16(x);           // RNE, hw cvt on gfx950
    union { __hip_bfloat16 h; unsigned short u; } v; v.h = h;
    return v.u;
}

// ---------------------------------------------------------------------------
// Kernel A: per (n, chunk-of-512-windows): layers 1+2, masked column sums.
// Wave w owns output channels [32w, 32w+32); all 64 rows of each step.
// xw layout: row r occupies 16B slots {2r, 2r+1} (k0..8 data, k9..15 zero),
// each slot S stored at S ^ ((S>>3)&3) -> quarter-wave b128 reads are 2-way
// (free) instead of 4-8-way. The XOR depends only on S, so the overread
// into neighbor rows (masked by zeroed A columns k>=9) stays consistent.
// ---------------------------------------------------------------------------
__global__ __launch_bounds__(256, 6) void pen_inner(
    const float* __restrict__ x,
    const float* __restrict__ w1, const float* __restrict__ b1,
    const float* __restrict__ w2, const float* __restrict__ b2,
    float* __restrict__ partials)
{
    __shared__ __align__(16) unsigned short xw[4160];      // 520 slots, 8.3 KB
    __shared__ __align__(16) unsigned short h1s[SR * HH];  // 16.4 KB

    const int tid  = threadIdx.x;
    const int wave = tid >> 6;
    const int lane = tid & 63;
    const int lr   = lane & 15;   // MFMA "lane&15" index (A-row / B-col / D-col)
    const int lq   = lane >> 4;   // 0..3

    const int bx    = blockIdx.x;
    const int n     = bx >> 3;
    const int chunk = bx & 7;
    const int l0c   = chunk * RPC;

    const float* xn = x + n * (MM * TT);

    // ---- preload weight fragments; biases go into the MFMA C operand ----
    const int fo0 = wave * 2;              // this wave's two 16-wide o-fragments
    bf16x8 w1f[2];                         // A1 = W1^T : [c][k], k>=9 zeroed
    bf16x8 w2f[2][4];                      // A2 = W2^T : [o][i], 4 k-chunks of 32
    f32x4  b1f[2], b2f[2];                 // bias in D-layout (row = lq*4+j)
    #pragma unroll
    for (int f = 0; f < 2; ++f) {
        const int c = (fo0 + f) * 16 + lr;
        bf16x8 a;
        #pragma unroll
        for (int e = 0; e < 8; ++e) {
            int k = lq * 8 + e;
            a[e] = (short)((k < 9) ? f2bf(w1[k * HH + c]) : (unsigned short)0);
        }
        w1f[f] = a;
        #pragma unroll
        for (int kk = 0; kk < 4; ++kk) {
            bf16x8 wv;
            #pragma unroll
            for (int e = 0; e < 8; ++e)
                wv[e] = (short)f2bf(w2[(kk * 32 + lq * 8 + e) * HH + c]);
            w2f[f][kk] = wv;
        }
        #pragma unroll
        for (int j = 0; j < 4; ++j) {
            b1f[f][j] = b1[(fo0 + f) * 16 + lq * 4 + j];
            b2f[f][j] = b2[(fo0 + f) * 16 + lq * 4 + j];
        }
    }

    // per-lane swizzled xw read offset (halfwords): slot c0=2*lr+lq, XOR'd
    const int c0 = 2 * lr + lq;
    const int xo = ((c0 ^ ((c0 >> 3) & 3)) << 3);

    if (tid < 64) xw[4096 + tid] = 0;      // pad slots 512..519 (lq overread, r=255)

    float colsum[2][4] = {{0.f,0.f,0.f,0.f},{0.f,0.f,0.f,0.f}};

    for (int half = 0; half < HALVES; ++half) {
        const int lbase = l0c + half * RPH;

        // ---- stage this half's 256 window-rows as bf16 (swizzled slots) ----
        // Safe: all xw reads of the previous half precede its last mid-step
        // barrier, which every thread has passed before reaching here.
        {
            const int r = tid;             // RPH == blockDim
            const int sw = (r >> 2) & 3;
            #pragma unroll
            for (int k = 0; k < 8; ++k) {  // k = i*3+m, slot 2r
                const int i = k / 3;
                const int m = k - i * 3;
                const int t = lbase + r + i;
                const float v = (t < TT) ? xn[m * TT + t] : 0.f;
                xw[((2 * r) ^ sw) * 8 + k] = f2bf(v);
            }
            {                               // k=8 + zero pad, slot 2r+1
                const int t = lbase + r + 2;
                const float v = (t < TT) ? xn[2 * TT + t] : 0.f;
                u16x4 a; a[0] = f2bf(v); a[1] = 0; a[2] = 0; a[3] = 0;
                u16x4 z; z[0] = 0; z[1] = 0; z[2] = 0; z[3] = 0;
                const int slot = (2 * r + 1) ^ sw;
                *(u16x4*)&xw[slot * 8]     = a;
                *(u16x4*)&xw[slot * 8 + 4] = z;
            }
        }

        for (int s = 0; s < STEPS; ++s) {
            __syncthreads();   // staging done (s==0) / h1s reads of prev step done

            // ---- layer 1: D1[c][r] = W1^T @ xin^T + b1 (bias via C operand) ----
            f32x4 acc1[2][4];
            #pragma unroll
            for (int rf = 0; rf < 4; ++rf) {
                bf16x8 bfrag = *(const bf16x8*)&xw[s * 1024 + rf * 256 + xo];
                acc1[0][rf] = __builtin_amdgcn_mfma_f32_16x16x32_bf16(w1f[0], bfrag, b1f[0], 0, 0, 0);
                acc1[1][rf] = __builtin_amdgcn_mfma_f32_16x16x32_bf16(w1f[1], bfrag, b1f[1], 0, 0, 0);
            }

            // ---- relu + pack + swizzled LDS store: h1s[r][c], idx ^= (r&7)<<3 ----
            #pragma unroll
            for (int rf = 0; rf < 4; ++rf) {
                const int r   = rf * 16 + lr;
                const int swz = (r & 7) << 3;
                #pragma unroll
                for (int f = 0; f < 2; ++f) {
                    const int cb = (fo0 + f) * 16 + lq * 4;
                    unsigned p0 = f2bf(fmaxf(acc1[f][rf][0], 0.f));
                    unsigned p1 = f2bf(fmaxf(acc1[f][rf][1], 0.f));
                    unsigned p2 = f2bf(fmaxf(acc1[f][rf][2], 0.f));
                    unsigned p3 = f2bf(fmaxf(acc1[f][rf][3], 0.f));
                    u32x2 pk;
                    pk[0] = p0 | (p1 << 16);
                    pk[1] = p2 | (p3 << 16);
                    *(u32x2*)&h1s[r * HH + (cb ^ swz)] = pk;
                }
            }
            __syncthreads();

            // ---- layer 2: D2[o][r] = W2^T @ h1^T + b2, 4 K-chunks ----
            f32x4 acc2[2][4];
            #pragma unroll
            for (int rf = 0; rf < 4; ++rf) {
                const int r   = rf * 16 + lr;
                const int swz = (r & 7) << 3;
                bf16x8 hf[4];
                #pragma unroll
                for (int kk = 0; kk < 4; ++kk)
                    hf[kk] = *(const bf16x8*)&h1s[r * HH + ((kk * 32 + lq * 8) ^ swz)];
                acc2[0][rf] = __builtin_amdgcn_mfma_f32_16x16x32_bf16(w2f[0][0], hf[0], b2f[0], 0, 0, 0);
                acc2[1][rf] = __builtin_amdgcn_mfma_f32_16x16x32_bf16(w2f[1][0], hf[0], b2f[1], 0, 0, 0);
                #pragma unroll
                for (int kk = 1; kk < 4; ++kk) {
                    acc2[0][rf] = __builtin_amdgcn_mfma_f32_16x16x32_bf16(w2f[0][kk], hf[kk], acc2[0][rf], 0, 0, 0);
                    acc2[1][rf] = __builtin_amdgcn_mfma_f32_16x16x32_bf16(w2f[1][kk], hf[kk], acc2[1][rf], 0, 0, 0);
                }
            }

            // ---- relu + column-sum; tail mask only on the one affected rf ----
            const bool tailstep = (chunk == CHUNKS - 1) && (half == HALVES - 1)
                                  && (s == STEPS - 1);
            #pragma unroll
            for (int rf = 0; rf < 4; ++rf) {
                if (tailstep && rf == 3) {              // rows 4080+lr; valid iff lr<14
                    const bool valid = lr < 14;
                    #pragma unroll
                    for (int f = 0; f < 2; ++f)
                        #pragma unroll
                        for (int j = 0; j < 4; ++j) {
                            float v = fmaxf(acc2[f][rf][j], 0.f);
                            if (valid) colsum[f][j] += v;
                        }
                } else {
                    #pragma unroll
                    for (int f = 0; f < 2; ++f)
                        #pragma unroll
                        for (int j = 0; j < 4; ++j)
                            colsum[f][j] += fmaxf(acc2[f][rf][j], 0.f);
                }
            }
        }
    }

    // ---- reduce colsum over the 16 r-lanes, write block partial (no atomics) ----
    #pragma unroll
    for (int f = 0; f < 2; ++f)
        #pragma unroll
        for (int j = 0; j < 4; ++j) {
            float v = colsum[f][j];
            #pragma unroll
            for (int msk = 1; msk < 16; msk <<= 1)
                v += __shfl_xor(v, msk, 64);
            if (lr == 0) {
                const int o = (fo0 + f) * 16 + lq * 4 + j;
                partials[(n * CHUNKS + chunk) * HH + o] = v;
            }
        }
}

// ---------------------------------------------------------------------------
// Kernel B: tail in fp32. inner = sum partials; oi = inner@W3 + L*b3;
// io = [x[:, :, :2] flat (6), oi]; g = relu(io@rw1+rb1); out = g@rw2+rb2.
// ---------------------------------------------------------------------------
__global__ __launch_bounds__(128) void pen_outer(
    const float* __restrict__ x,
    const float* __restrict__ w3, const float* __restrict__ b3,
    const float* __restrict__ rw1, const float* __restrict__ rb1,
    const float* __restrict__ rw2, const float* __restrict__ rb2,
    const float* __restrict__ partials,
    float* __restrict__ out)
{
    __shared__ float S[HH];
    __shared__ float IO[136];
    __shared__ float G[HH];
    const int n = blockIdx.x;
    const int c = threadIdx.x;

    float s = 0.f;
    #pragma unroll
    for (int ch = 0; ch < CHUNKS; ++ch)
        s += partials[(n * CHUNKS + ch) * HH + c];
    S[c] = s;
    if (c < 6) IO[c] = x[n * (MM * TT) + (c >> 1) * TT + (c & 1)];
    __syncthreads();

    float oi = (float)LL * b3[c];
    for (int k = 0; k < HH; ++k) oi += S[k] * w3[k * HH + c];
    IO[6 + c] = oi;
    __syncthreads();

    float g = rb1[c];
    for (int k = 0; k < 134; ++k) g += IO[k] * rw1[k * HH + c];
    G[c] = fmaxf(g, 0.f);
    __syncthreads();

    if (c < 10) {
        float o = rb2[c];
        for (int k = 0; k < HH; ++k) o += G[k] * rw2[k * 10 + c];
        out[n * 10 + c] = o;
    }
}

// ---------------------------------------------------------------------------
extern "C" void kernel_launch(void* const* d_in, const int* in_sizes, int n_in,
                              void* d_out, int out_size, void* d_ws, size_t ws_size,
                              hipStream_t stream)
{
    (void)in_sizes; (void)n_in; (void)out_size; (void)ws_size;
    const float* x   = (const float*)d_in[0];
    const float* w1  = (const float*)d_in[1];
    const float* b1  = (const float*)d_in[2];
    const float* w2  = (const float*)d_in[3];
    const float* b2  = (const float*)d_in[4];
    const float* w3  = (const float*)d_in[5];
    const float* b3  = (const float*)d_in[6];
    const float* rw1 = (const float*)d_in[7];
    const float* rb1 = (const float*)d_in[8];
    const float* rw2 = (const float*)d_in[9];
    const float* rb2 = (const float*)d_in[10];

    float* partials = (float*)d_ws;   // NN*CHUNKS*HH floats = 1 MiB of scratch

    pen_inner<<<NN * CHUNKS, 256, 0, stream>>>(x, w1, b1, w2, b2, partials);
    pen_outer<<<NN, 128, 0, stream>>>(x, w3, b3, rw1, rb1, rw2, rb2, partials,
                                      (float*)d_out);
}

// Round 5
// 73.908 us; speedup vs baseline: 5.1198x; 5.1198x over previous
//
#include <hip/hip_runtime.h>
#include <hip/hip_bf16.h>

// PartiallyExchangeableNetwork on MI355X (gfx950)
// N=256, M=3, T=4096, ORDER=2 -> L=4094 windows, H=128, OUT=10
//
// h1 = relu(xin @ W1 + b1); h2 = relu(h1 @ W2 + b2); colsum over L.
// Layer 3 folded through the sum: sum_l(h2@W3+b3) = (sum_l h2)@W3 + L*b3 (tail kernel).

#define NN 256
#define MM 3
#define TT 4096
#define LL 4094
#define HH 128
#define CHUNKS 8
#define RPC 512          // rows (windows) per chunk (2 halves of 256)
#define RPH 256          // rows per staged half
#define HALVES 2
#define STEPS 4          // 64-row steps per half
#define SR 64            // rows per step (block tile)
#define XROW 24          // xw row stride in halfwords (48 B): bank-conflict-free

typedef __attribute__((ext_vector_type(8))) short bf16x8;
typedef __attribute__((ext_vector_type(4))) float f32x4;
typedef __attribute__((ext_vector_type(4))) unsigned short u16x4;
typedef __attribute__((ext_vector_type(2))) unsigned int u32x2;

__device__ __forceinline__ unsigned short f2bf(float x) {
    __hip_bfloat16 h = __float2bfloat16(x);           // RNE, hw cvt on gfx950
    union { __hip_bfloat16 h; unsigned short u; } v; v.h = h;
    return v.u;
}

// ---------------------------------------------------------------------------
// Kernel A: per (n, chunk-of-512-windows): layers 1+2, masked column sums.
// Wave w owns output channels [32w, 32w+32); all 64 rows of each step.
//
// xw layout: row r at halfwords [24r, 24r+24): k0..8 data, k9..23 zero.
// L1 B-fragment read: byte 48r + 16lq -> bank (12*lr + 4*lq)&31 = 2 lanes per
// 4-bank group per quarter-wave (free, m136); 16B-aligned. lq>=2 lanes read
// row-r zero pad / row-(r+1) data, both multiplied by zeroed A columns k>=9.
// ---------------------------------------------------------------------------
__global__ __launch_bounds__(256, 4) void pen_inner(
    const float* __restrict__ x,
    const float* __restrict__ w1, const float* __restrict__ b1,
    const float* __restrict__ w2, const float* __restrict__ b2,
    float* __restrict__ partials)
{
    __shared__ __align__(16) unsigned short xw[XROW * (RPH + 1) + 8]; // 12.4 KB
    __shared__ __align__(16) unsigned short h1s[SR * HH];             // 16.4 KB

    const int tid  = threadIdx.x;
    const int wave = tid >> 6;
    const int lane = tid & 63;
    const int lr   = lane & 15;   // MFMA "lane&15" index (A-row / B-col / D-col)
    const int lq   = lane >> 4;   // 0..3

    const int bx    = blockIdx.x;
    const int n     = bx >> 3;
    const int chunk = bx & 7;
    const int l0c   = chunk * RPC;

    const float* xn = x + n * (MM * TT);

    // ---- preload weight fragments; biases go into the MFMA C operand ----
    const int fo0 = wave * 2;              // this wave's two 16-wide o-fragments
    bf16x8 w1f[2];                         // A1 = W1^T : [c][k], k>=9 zeroed
    bf16x8 w2f[2][4];                      // A2 = W2^T : [o][i], 4 k-chunks of 32
    f32x4  b1f[2], b2f[2];                 // bias in D-layout (row = lq*4+j)
    #pragma unroll
    for (int f = 0; f < 2; ++f) {
        const int c = (fo0 + f) * 16 + lr;
        bf16x8 a;
        #pragma unroll
        for (int e = 0; e < 8; ++e) {
            int k = lq * 8 + e;
            a[e] = (short)((k < 9) ? f2bf(w1[k * HH + c]) : (unsigned short)0);
        }
        w1f[f] = a;
        #pragma unroll
        for (int kk = 0; kk < 4; ++kk) {
            bf16x8 wv;
            #pragma unroll
            for (int e = 0; e < 8; ++e)
                wv[e] = (short)f2bf(w2[(kk * 32 + lq * 8 + e) * HH + c]);
            w2f[f][kk] = wv;
        }
        #pragma unroll
        for (int j = 0; j < 4; ++j) {
            b1f[f][j] = b1[(fo0 + f) * 16 + lq * 4 + j];
            b2f[f][j] = b2[(fo0 + f) * 16 + lq * 4 + j];
        }
    }

    // zero the tail row (row 256, read by lq=3 overread at r=255) once
    if (tid < XROW + 8) xw[XROW * RPH + tid] = 0;

    // per-lane xw read offset (halfwords)
    const int xo = XROW * lr + 8 * lq;

    float colsum[2][4] = {{0.f,0.f,0.f,0.f},{0.f,0.f,0.f,0.f}};

    for (int half = 0; half < HALVES; ++half) {
        const int lbase = l0c + half * RPH;

        // ---- stage this half's 256 window-rows as bf16 ----
        // Safe: all xw reads of the previous half precede its last mid-step
        // barrier, which every thread has passed before reaching here.
        {
            const int r = tid;             // RPH == blockDim
            unsigned short kv[9];
            #pragma unroll
            for (int k = 0; k < 9; ++k) {  // k = i*3+m; coalesced over r per k
                const int i = k / 3;
                const int m = k - i * 3;
                const int t = lbase + r + i;
                kv[k] = (t < TT) ? f2bf(xn[m * TT + t]) : (unsigned short)0;
            }
            u16x4 s0, s1, s2;
            s0[0] = kv[0]; s0[1] = kv[1]; s0[2] = kv[2]; s0[3] = kv[3];
            s1[0] = kv[4]; s1[1] = kv[5]; s1[2] = kv[6]; s1[3] = kv[7];
            s2[0] = kv[8]; s2[1] = 0; s2[2] = 0; s2[3] = 0;
            u16x4 z; z[0] = 0; z[1] = 0; z[2] = 0; z[3] = 0;
            *(u16x4*)&xw[XROW * r]      = s0;
            *(u16x4*)&xw[XROW * r + 4]  = s1;
            *(u16x4*)&xw[XROW * r + 8]  = s2;
            *(u16x4*)&xw[XROW * r + 12] = z;
            *(u16x4*)&xw[XROW * r + 16] = z;
            *(u16x4*)&xw[XROW * r + 20] = z;
        }

        for (int s = 0; s < STEPS; ++s) {
            __syncthreads();   // staging done (s==0) / h1s reads of prev step done

            // ---- layer 1: D1[c][r] = W1^T @ xin^T + b1 (bias via C operand) ----
            f32x4 acc1[2][4];
            #pragma unroll
            for (int rf = 0; rf < 4; ++rf) {
                bf16x8 bfrag = *(const bf16x8*)&xw[s * (XROW * SR) + rf * (XROW * 16) + xo];
                acc1[0][rf] = __builtin_amdgcn_mfma_f32_16x16x32_bf16(w1f[0], bfrag, b1f[0], 0, 0, 0);
                acc1[1][rf] = __builtin_amdgcn_mfma_f32_16x16x32_bf16(w1f[1], bfrag, b1f[1], 0, 0, 0);
            }

            // ---- relu + pack + swizzled LDS store: h1s[r][c], idx ^= (r&7)<<3 ----
            #pragma unroll
            for (int rf = 0; rf < 4; ++rf) {
                const int r   = rf * 16 + lr;
                const int swz = (r & 7) << 3;
                #pragma unroll
                for (int f = 0; f < 2; ++f) {
                    const int cb = (fo0 + f) * 16 + lq * 4;
                    unsigned p0 = f2bf(fmaxf(acc1[f][rf][0], 0.f));
                    unsigned p1 = f2bf(fmaxf(acc1[f][rf][1], 0.f));
                    unsigned p2 = f2bf(fmaxf(acc1[f][rf][2], 0.f));
                    unsigned p3 = f2bf(fmaxf(acc1[f][rf][3], 0.f));
                    u32x2 pk;
                    pk[0] = p0 | (p1 << 16);
                    pk[1] = p2 | (p3 << 16);
                    *(u32x2*)&h1s[r * HH + (cb ^ swz)] = pk;
                }
            }
            __syncthreads();

            // ---- layer 2: D2[o][r] = W2^T @ h1^T + b2, 4 K-chunks ----
            f32x4 acc2[2][4];
            #pragma unroll
            for (int rf = 0; rf < 4; ++rf) {
                const int r   = rf * 16 + lr;
                const int swz = (r & 7) << 3;
                bf16x8 hf[4];
                #pragma unroll
                for (int kk = 0; kk < 4; ++kk)
                    hf[kk] = *(const bf16x8*)&h1s[r * HH + ((kk * 32 + lq * 8) ^ swz)];
                acc2[0][rf] = __builtin_amdgcn_mfma_f32_16x16x32_bf16(w2f[0][0], hf[0], b2f[0], 0, 0, 0);
                acc2[1][rf] = __builtin_amdgcn_mfma_f32_16x16x32_bf16(w2f[1][0], hf[0], b2f[1], 0, 0, 0);
                #pragma unroll
                for (int kk = 1; kk < 4; ++kk) {
                    acc2[0][rf] = __builtin_amdgcn_mfma_f32_16x16x32_bf16(w2f[0][kk], hf[kk], acc2[0][rf], 0, 0, 0);
                    acc2[1][rf] = __builtin_amdgcn_mfma_f32_16x16x32_bf16(w2f[1][kk], hf[kk], acc2[1][rf], 0, 0, 0);
                }
            }

            // ---- relu + column-sum; tail mask only on the one affected rf ----
            const bool tailstep = (chunk == CHUNKS - 1) && (half == HALVES - 1)
                                  && (s == STEPS - 1);
            #pragma unroll
            for (int rf = 0; rf < 4; ++rf) {
                if (tailstep && rf == 3) {              // rows 4080+lr; valid iff lr<14
                    const bool valid = lr < 14;
                    #pragma unroll
                    for (int f = 0; f < 2; ++f)
                        #pragma unroll
                        for (int j = 0; j < 4; ++j) {
                            float v = fmaxf(acc2[f][rf][j], 0.f);
                            if (valid) colsum[f][j] += v;
                        }
                } else {
                    #pragma unroll
                    for (int f = 0; f < 2; ++f)
                        #pragma unroll
                        for (int j = 0; j < 4; ++j)
                            colsum[f][j] += fmaxf(acc2[f][rf][j], 0.f);
                }
            }
        }
    }

    // ---- reduce colsum over the 16 r-lanes, write block partial (no atomics) ----
    #pragma unroll
    for (int f = 0; f < 2; ++f)
        #pragma unroll
        for (int j = 0; j < 4; ++j) {
            float v = colsum[f][j];
            #pragma unroll
            for (int msk = 1; msk < 16; msk <<= 1)
                v += __shfl_xor(v, msk, 64);
            if (lr == 0) {
                const int o = (fo0 + f) * 16 + lq * 4 + j;
                partials[(n * CHUNKS + chunk) * HH + o] = v;
            }
        }
}

// ---------------------------------------------------------------------------
// Kernel B: tail in fp32. inner = sum partials; oi = inner@W3 + L*b3;
// io = [x[:, :, :2] flat (6), oi]; g = relu(io@rw1+rb1); out = g@rw2+rb2.
// ---------------------------------------------------------------------------
__global__ __launch_bounds__(128) void pen_outer(
    const float* __restrict__ x,
    const float* __restrict__ w3, const float* __restrict__ b3,
    const float* __restrict__ rw1, const float* __restrict__ rb1,
    const float* __restrict__ rw2, const float* __restrict__ rb2,
    const float* __restrict__ partials,
    float* __restrict__ out)
{
    __shared__ float S[HH];
    __shared__ float IO[136];
    __shared__ float G[HH];
    const int n = blockIdx.x;
    const int c = threadIdx.x;

    float s = 0.f;
    #pragma unroll
    for (int ch = 0; ch < CHUNKS; ++ch)
        s += partials[(n * CHUNKS + ch) * HH + c];
    S[c] = s;
    if (c < 6) IO[c] = x[n * (MM * TT) + (c >> 1) * TT + (c & 1)];
    __syncthreads();

    float oi = (float)LL * b3[c];
    for (int k = 0; k < HH; ++k) oi += S[k] * w3[k * HH + c];
    IO[6 + c] = oi;
    __syncthreads();

    float g = rb1[c];
    for (int k = 0; k < 134; ++k) g += IO[k] * rw1[k * HH + c];
    G[c] = fmaxf(g, 0.f);
    __syncthreads();

    if (c < 10) {
        float o = rb2[c];
        for (int k = 0; k < HH; ++k) o += G[k] * rw2[k * 10 + c];
        out[n * 10 + c] = o;
    }
}

// ---------------------------------------------------------------------------
extern "C" void kernel_launch(void* const* d_in, const int* in_sizes, int n_in,
                              void* d_out, int out_size, void* d_ws, size_t ws_size,
                              hipStream_t stream)
{
    (void)in_sizes; (void)n_in; (void)out_size; (void)ws_size;
    const float* x   = (const float*)d_in[0];
    const float* w1  = (const float*)d_in[1];
    const float* b1  = (const float*)d_in[2];
    const float* w2  = (const float*)d_in[3];
    const float* b2  = (const float*)d_in[4];
    const float* w3  = (const float*)d_in[5];
    const float* b3  = (const float*)d_in[6];
    const float* rw1 = (const float*)d_in[7];
    const float* rb1 = (const float*)d_in[8];
    const float* rw2 = (const float*)d_in[9];
    const float* rb2 = (const float*)d_in[10];

    float* partials = (float*)d_ws;   // NN*CHUNKS*HH floats = 1 MiB of scratch

    pen_inner<<<NN * CHUNKS, 256, 0, stream>>>(x, w1, b1, w2, b2, partials);
    pen_outer<<<NN, 128, 0, stream>>>(x, w3, b3, rw1, rb1, rw2, rb2, partials,
                                      (float*)d_out);
}